// Round 1
// baseline (2293.425 us; speedup 1.0000x reference)
//
#include <hip/hip_runtime.h>
#include <math.h>

#define NN 200000
#define NE 50000
#define D 128
#define GDIM 384   // 3*MEM

__device__ __forceinline__ float sigmoidf_(float x) { return 1.0f / (1.0f + expf(-x)); }

// ---------------- kernel 1: init last_pos ----------------
__global__ void k_init(int* __restrict__ last_pos) {
    int i = blockIdx.x * blockDim.x + threadIdx.x;
    if (i < NN) last_pos[i] = -1;
}

// ---------------- kernel 2: scatter max position ----------------
__global__ void k_lastpos(const int* __restrict__ src, const int* __restrict__ dst,
                          int* __restrict__ last_pos) {
    int i = blockIdx.x * blockDim.x + threadIdx.x;
    if (i < 2 * NE) {
        int id = (i < NE) ? src[i] : dst[i - NE];
        atomicMax(&last_pos[id], i);
    }
}

// ---------------- kernel 3: GRU update for is_last messages ----------------
// block = 384 threads, GMB=16 messages/block. thread j computes gate row j
// (j<128 -> r, <256 -> z, <384 -> n) for all 16 messages.
#define GMB 16
__global__ __launch_bounds__(384) void k_gru(
    const float* __restrict__ memp, const float* __restrict__ lup,
    const float* __restrict__ tp, const float* __restrict__ msgp,
    const int* __restrict__ srcp, const int* __restrict__ dstp,
    const float* __restrict__ twp, const float* __restrict__ tbp,
    const float* __restrict__ Wih, const float* __restrict__ bih,
    const float* __restrict__ Whh, const float* __restrict__ bhh,
    const int* __restrict__ last_pos,
    float* __restrict__ mem_new, float* __restrict__ lu_new, float* __restrict__ denom)
{
    __shared__ float Xf[GMB][GDIM];                       // [mem_id | mem_other | msg | te]
    __shared__ float s_r[GMB][D], s_z[GMB][D], s_in[GMB][D], s_hn[GMB][D];
    __shared__ int sid[GMB], sother[GMB], se[GMB], slast[GMB];
    __shared__ float st[GMB], sdt[GMB];

    int tid = threadIdx.x;
    int i0 = blockIdx.x * GMB;
    if (tid < GMB) {
        int i = i0 + tid;
        int e = (i < NE) ? i : (i - NE);
        int id    = (i < NE) ? srcp[e] : dstp[e];
        int other = (i < NE) ? dstp[e] : srcp[e];
        sid[tid] = id; sother[tid] = other; se[tid] = e;
        float tt = tp[e];
        st[tid] = tt;
        sdt[tid] = tt - lup[id];
        slast[tid] = (last_pos[id] == i) ? 1 : 0;
    }
    __syncthreads();

    {   // stage X: thread tid = channel c, loop messages
        int c = tid;
        for (int m = 0; m < GMB; ++m) {
            float val;
            if (c < D)               val = memp[sid[m] * D + c];
            else if (c < 2 * D)      val = memp[sother[m] * D + (c - D)];
            else if (c < 2 * D + 64) val = msgp[se[m] * 64 + (c - 2 * D)];
            else                     val = cosf(sdt[m] * twp[c - (2 * D + 64)] + tbp[c - (2 * D + 64)]);
            Xf[m][c] = val;
        }
    }
    __syncthreads();

    float acc_i[GMB], acc_h[GMB];
    #pragma unroll
    for (int m = 0; m < GMB; ++m) { acc_i[m] = 0.f; acc_h[m] = 0.f; }

    const float4* wi = (const float4*)(Wih + tid * GDIM);
    for (int k4 = 0; k4 < GDIM / 4; ++k4) {
        float4 w = wi[k4];
        #pragma unroll
        for (int m = 0; m < GMB; ++m) {
            float4 x = ((const float4*)Xf[m])[k4];        // broadcast LDS read
            acc_i[m] += w.x * x.x + w.y * x.y + w.z * x.z + w.w * x.w;
        }
    }
    const float4* wh = (const float4*)(Whh + tid * D);
    for (int k4 = 0; k4 < D / 4; ++k4) {
        float4 w = wh[k4];
        #pragma unroll
        for (int m = 0; m < GMB; ++m) {
            float4 x = ((const float4*)Xf[m])[k4];        // h = first 128 of X
            acc_h[m] += w.x * x.x + w.y * x.y + w.z * x.z + w.w * x.w;
        }
    }
    float bi = bih[tid], bh = bhh[tid];
    int p = tid >> 7, c = tid & 127;
    #pragma unroll
    for (int m = 0; m < GMB; ++m) {
        float gi = acc_i[m] + bi, gh = acc_h[m] + bh;
        if (p == 0)      s_r[m][c]  = gi + gh;
        else if (p == 1) s_z[m][c]  = gi + gh;
        else           { s_in[m][c] = gi; s_hn[m][c] = gh; }
    }
    __syncthreads();

    for (int f = tid; f < GMB * D; f += 384) {
        int m = f >> 7, cc = f & 127;
        if (slast[m]) {
            float r  = sigmoidf_(s_r[m][cc]);
            float zg = sigmoidf_(s_z[m][cc]);
            float n  = tanhf(s_in[m][cc] + r * s_hn[m][cc]);
            float h  = Xf[m][cc];
            mem_new[sid[m] * D + cc] = (1.f - zg) * n + zg * h;
        }
    }
    if (tid < GMB && slast[tid]) {
        int id = sid[tid];
        lu_new[id] = fmaxf(lup[id], st[tid]);
        denom[id * 2] = 0.f; denom[id * 2 + 1] = 0.f;   // dst subset of touched nodes
    }
}

// ---------------- kernel 4: skip connection z = Wskip@mem_new + bskip (touched rows) ----
#define SMB 16
__global__ __launch_bounds__(128) void k_skip(
    const int* __restrict__ srcp, const int* __restrict__ dstp,
    const int* __restrict__ last_pos, const float* __restrict__ mem_new,
    const float* __restrict__ Wskip, const float* __restrict__ bskip,
    float* __restrict__ zbuf)
{
    __shared__ float Xf[SMB][D];
    __shared__ int sid[SMB], slast[SMB];
    int tid = threadIdx.x;
    int i0 = blockIdx.x * SMB;
    if (tid < SMB) {
        int i = i0 + tid;
        int id = (i < NE) ? srcp[i] : dstp[i - NE];
        sid[tid] = id;
        slast[tid] = (last_pos[id] == i) ? 1 : 0;
    }
    __syncthreads();
    for (int m = 0; m < SMB; ++m)
        Xf[m][tid] = slast[m] ? mem_new[sid[m] * D + tid] : 0.f;
    __syncthreads();
    float acc[SMB];
    #pragma unroll
    for (int m = 0; m < SMB; ++m) acc[m] = 0.f;
    const float4* wr = (const float4*)(Wskip + tid * D);
    for (int k4 = 0; k4 < D / 4; ++k4) {
        float4 w = wr[k4];
        #pragma unroll
        for (int m = 0; m < SMB; ++m) {
            float4 x = ((const float4*)Xf[m])[k4];
            acc[m] += w.x * x.x + w.y * x.y + w.z * x.z + w.w * x.w;
        }
    }
    float b = bskip[tid];
    for (int m = 0; m < SMB; ++m)
        if (slast[m]) zbuf[sid[m] * D + tid] = acc[m] + b;
}

// ---------------- kernel 5: per-edge k,v,q + logits + exp + denom ----------------
// block = 384: role 0 -> k (Wk*mem_s + We*ea), role 1 -> v, role 2 -> q (Wq*mem_d)
#define AEB 8
__global__ __launch_bounds__(384) void k_attnA(
    const int* __restrict__ srcp, const int* __restrict__ dstp,
    const float* __restrict__ tp, const float* __restrict__ msgp,
    const float* __restrict__ twp, const float* __restrict__ tbp,
    const float* __restrict__ lu_new, const float* __restrict__ mem_new,
    const float* __restrict__ Wq, const float* __restrict__ bq,
    const float* __restrict__ Wk, const float* __restrict__ bk,
    const float* __restrict__ Wv, const float* __restrict__ bv,
    const float* __restrict__ We,
    float* __restrict__ vbuf, float* __restrict__ abuf, float* __restrict__ denom)
{
    __shared__ float Xf[AEB][GDIM];         // [mem_s(128) | mem_d(128) | te(64) | msg(64)]
    __shared__ float kL[AEB][D], qL[AEB][D];
    __shared__ int ssrc[AEB], sdst[AEB];
    __shared__ float srel[AEB];
    int tid = threadIdx.x;
    int e0 = blockIdx.x * AEB;
    if (tid < AEB) {
        int e = e0 + tid;
        int s = srcp[e], dd = dstp[e];
        ssrc[tid] = s; sdst[tid] = dd;
        srel[tid] = lu_new[s] - tp[e];      // rel_t (uses NEW last_update)
    }
    __syncthreads();
    {
        int c = tid;
        for (int m = 0; m < AEB; ++m) {
            float val;
            if (c < D)               val = mem_new[ssrc[m] * D + c];
            else if (c < 2 * D)      val = mem_new[sdst[m] * D + (c - D)];
            else if (c < 2 * D + 64) val = cosf(srel[m] * twp[c - 2 * D] + tbp[c - 2 * D]);
            else                     val = msgp[(e0 + m) * 64 + (c - (2 * D + 64))];
            Xf[m][c] = val;
        }
    }
    __syncthreads();
    int role = tid >> 7, j = tid & 127;
    float acc[AEB];
    if (role < 2) {
        const float* Wm = (role == 0) ? Wk : Wv;
        float b = ((role == 0) ? bk : bv)[j];
        #pragma unroll
        for (int m = 0; m < AEB; ++m) acc[m] = b;
        const float4* wm4 = (const float4*)(Wm + j * D);
        const float4* we4 = (const float4*)(We + j * D);
        for (int k4 = 0; k4 < D / 4; ++k4) {
            float4 wa = wm4[k4], wb = we4[k4];
            #pragma unroll
            for (int m = 0; m < AEB; ++m) {
                float4 xs = ((const float4*)Xf[m])[k4];       // mem_s
                float4 xe = ((const float4*)Xf[m])[64 + k4];  // edge attr [te|msg]
                acc[m] += wa.x * xs.x + wa.y * xs.y + wa.z * xs.z + wa.w * xs.w
                        + wb.x * xe.x + wb.y * xe.y + wb.z * xe.z + wb.w * xe.w;
            }
        }
    } else {
        float b = bq[j];
        #pragma unroll
        for (int m = 0; m < AEB; ++m) acc[m] = b;
        const float4* wq4 = (const float4*)(Wq + j * D);
        for (int k4 = 0; k4 < D / 4; ++k4) {
            float4 wa = wq4[k4];
            #pragma unroll
            for (int m = 0; m < AEB; ++m) {
                float4 xd = ((const float4*)Xf[m])[32 + k4];  // mem_d
                acc[m] += wa.x * xd.x + wa.y * xd.y + wa.z * xd.z + wa.w * xd.w;
            }
        }
    }
    #pragma unroll
    for (int m = 0; m < AEB; ++m) {
        if (role == 0)       kL[m][j] = acc[m];
        else if (role == 1)  vbuf[(e0 + m) * D + j] = acc[m];
        else                 qL[m][j] = acc[m];
    }
    __syncthreads();
    // logits: 16 (edge,head) pairs across 6 waves; exp without max-subtract
    // (logits ~N(0,1), |logit| < ~10 -> fp32 exp safe; mathematically identical)
    int w = tid >> 6, lane = tid & 63;
    for (int pr = w; pr < 2 * AEB; pr += 6) {
        int m = pr >> 1, h = pr & 1;
        float prod = qL[m][h * 64 + lane] * kL[m][h * 64 + lane];
        #pragma unroll
        for (int off = 32; off; off >>= 1) prod += __shfl_down(prod, off);
        if (lane == 0) {
            float a = expf(prod * 0.125f);                 // / sqrt(64)
            abuf[(e0 + m) * 2 + h] = a;
            atomicAdd(&denom[sdst[m] * 2 + h], a);
        }
    }
}

// ---------------- kernel 6: weighted scatter of v into z ----------------
__global__ void k_attnB(const int* __restrict__ dstp,
                        const float* __restrict__ abuf, const float* __restrict__ denom,
                        const float* __restrict__ vbuf, float* __restrict__ zbuf)
{
    int g = blockIdx.x * blockDim.x + threadIdx.x;    // exactly NE*128 threads
    int e = g >> 7, c = g & 127, h = c >> 6;
    int dd = dstp[e];
    float attn = abuf[e * 2 + h] / denom[dd * 2 + h];
    atomicAdd(&zbuf[dd * D + c], attn * vbuf[e * D + c]);
}

// ---------------- kernel 7: link predictor ----------------
#define LMB 8
__global__ __launch_bounds__(128) void k_link(
    const int* __restrict__ srcp, const int* __restrict__ dstp,
    const float* __restrict__ zbuf,
    const float* __restrict__ Wls, const float* __restrict__ bls,
    const float* __restrict__ Wld, const float* __restrict__ bld,
    const float* __restrict__ Wlf, const float* __restrict__ blf,
    float* __restrict__ outp)
{
    __shared__ float Xs[LMB][D], Xd[LMB][D];
    __shared__ int ss[LMB], sd[LMB];
    __shared__ float red[LMB][2];
    int tid = threadIdx.x;
    int e0 = blockIdx.x * LMB;
    if (tid < LMB) { ss[tid] = srcp[e0 + tid]; sd[tid] = dstp[e0 + tid]; }
    __syncthreads();
    for (int m = 0; m < LMB; ++m) {
        Xs[m][tid] = zbuf[ss[m] * D + tid];
        Xd[m][tid] = zbuf[sd[m] * D + tid];
    }
    __syncthreads();
    float acc[LMB];
    float binit = bls[tid] + bld[tid];
    #pragma unroll
    for (int m = 0; m < LMB; ++m) acc[m] = binit;
    const float4* ws4 = (const float4*)(Wls + tid * D);
    const float4* wd4 = (const float4*)(Wld + tid * D);
    for (int k4 = 0; k4 < D / 4; ++k4) {
        float4 wa = ws4[k4], wb = wd4[k4];
        #pragma unroll
        for (int m = 0; m < LMB; ++m) {
            float4 xs = ((const float4*)Xs[m])[k4];
            float4 xd = ((const float4*)Xd[m])[k4];
            acc[m] += wa.x * xs.x + wa.y * xs.y + wa.z * xs.z + wa.w * xs.w
                    + wb.x * xd.x + wb.y * xd.y + wb.z * xd.z + wb.w * xd.w;
        }
    }
    float wlf = Wlf[tid];
    int w = tid >> 6, lane = tid & 63;
    #pragma unroll
    for (int m = 0; m < LMB; ++m) {
        float part = fmaxf(acc[m], 0.f) * wlf;
        #pragma unroll
        for (int off = 32; off; off >>= 1) part += __shfl_down(part, off);
        if (lane == 0) red[m][w] = part;
    }
    __syncthreads();
    if (tid < LMB) outp[e0 + tid] = red[tid][0] + red[tid][1] + blf[0];
}

extern "C" void kernel_launch(void* const* d_in, const int* in_sizes, int n_in,
                              void* d_out, int out_size, void* d_ws, size_t ws_size,
                              hipStream_t stream)
{
    const float* memory      = (const float*)d_in[0];
    const float* last_update = (const float*)d_in[1];
    const float* t           = (const float*)d_in[2];
    const float* msg         = (const float*)d_in[3];
    const int*   src         = (const int*)d_in[4];
    const int*   dst         = (const int*)d_in[5];
    const float* time_w      = (const float*)d_in[6];
    const float* time_b      = (const float*)d_in[7];
    const float* gru_Wih     = (const float*)d_in[8];
    const float* gru_bih     = (const float*)d_in[9];
    const float* gru_Whh     = (const float*)d_in[10];
    const float* gru_bhh     = (const float*)d_in[11];
    const float* Wq          = (const float*)d_in[12];
    const float* bq          = (const float*)d_in[13];
    const float* Wk          = (const float*)d_in[14];
    const float* bk          = (const float*)d_in[15];
    const float* Wv          = (const float*)d_in[16];
    const float* bv          = (const float*)d_in[17];
    const float* We          = (const float*)d_in[18];
    const float* Wskip       = (const float*)d_in[19];
    const float* bskip       = (const float*)d_in[20];
    const float* Wls         = (const float*)d_in[21];
    const float* bls         = (const float*)d_in[22];
    const float* Wld         = (const float*)d_in[23];
    const float* bld         = (const float*)d_in[24];
    const float* Wlf         = (const float*)d_in[25];
    const float* blf         = (const float*)d_in[26];
    float* outp = (float*)d_out;

    // workspace layout (bytes), total 234,000,000
    char* ws = (char*)d_ws;
    int*   last_pos = (int*)  (ws + 0);            // N int
    float* lu_new   = (float*)(ws + 800000);       // N
    float* denom    = (float*)(ws + 1600000);      // 2N
    float* abuf     = (float*)(ws + 3200000);      // 2E
    float* vbuf     = (float*)(ws + 3600000);      // E*128
    float* mem_new  = (float*)(ws + 29200000);     // N*128 (touched rows only valid)
    float* zbuf     = (float*)(ws + 131600000);    // N*128 (touched rows only valid)

    k_init   <<<(NN + 255) / 256, 256, 0, stream>>>(last_pos);
    k_lastpos<<<(2 * NE + 255) / 256, 256, 0, stream>>>(src, dst, last_pos);
    k_gru    <<<2 * NE / GMB, 384, 0, stream>>>(memory, last_update, t, msg, src, dst,
                 time_w, time_b, gru_Wih, gru_bih, gru_Whh, gru_bhh, last_pos,
                 mem_new, lu_new, denom);
    k_skip   <<<2 * NE / SMB, 128, 0, stream>>>(src, dst, last_pos, mem_new, Wskip, bskip, zbuf);
    k_attnA  <<<NE / AEB, 384, 0, stream>>>(src, dst, t, msg, time_w, time_b, lu_new, mem_new,
                 Wq, bq, Wk, bk, Wv, bv, We, vbuf, abuf, denom);
    k_attnB  <<<NE * D / 256, 256, 0, stream>>>(dst, abuf, denom, vbuf, zbuf);
    k_link   <<<NE / LMB, 128, 0, stream>>>(src, dst, zbuf, Wls, bls, Wld, bld, Wlf, blf, outp);
}

// Round 2
// 997.877 us; speedup vs baseline: 2.2983x; 2.2983x over previous
//
#include <hip/hip_runtime.h>
#include <math.h>

#define NN 200000
#define NE 50000
#define D 128
#define GDIM 384   // 3*MEM

__device__ __forceinline__ float sigmoidf_(float x) { return 1.0f / (1.0f + expf(-x)); }

// round-to-nearest-even fp32 -> bf16 bits
__device__ __forceinline__ unsigned short f2bf(float f) {
    unsigned int u = __float_as_uint(f);
    u = (u + 0x7fffu + ((u >> 16) & 1u)) >> 16;
    return (unsigned short)u;
}

typedef short bf16x8 __attribute__((ext_vector_type(8)));
typedef float f32x4  __attribute__((ext_vector_type(4)));

// ---------------- kernel 1: init last_pos ----------------
__global__ void k_init(int* __restrict__ last_pos) {
    int i = blockIdx.x * blockDim.x + threadIdx.x;
    if (i < NN) last_pos[i] = -1;
}

// ---------------- kernel 2: scatter max position ----------------
__global__ void k_lastpos(const int* __restrict__ src, const int* __restrict__ dst,
                          int* __restrict__ last_pos) {
    int i = blockIdx.x * blockDim.x + threadIdx.x;
    if (i < 2 * NE) {
        int id = (i < NE) ? src[i] : dst[i - NE];
        atomicMax(&last_pos[id], i);
    }
}

// ---------------- kernel 2b: build fused bf16 GRU weight W''[512][384] ----------------
// rows 0..255   (r,z fused): Wih[n][k] + (k<128 ? Whh[n][k] : 0)
// rows 256..383 (i_n)      : Wih[n][k]
// rows 384..511 (h_n)      : Whh[n-128][k] for k<128 only (k>=128 never read)
__global__ void k_prepw(const float* __restrict__ Wih, const float* __restrict__ Whh,
                        unsigned short* __restrict__ wbuf) {
    int idx = blockIdx.x * 256 + threadIdx.x;     // over 512*96 float4-groups
    if (idx >= 512 * 96) return;
    int n = idx / 96;
    int c = (idx - n * 96) * 4;
    float4 v;
    if (n < 384) {
        v = *(const float4*)&Wih[n * 384 + c];
        if (n < 256 && c < 128) {
            const float4 w2 = *(const float4*)&Whh[n * 128 + c];
            v.x += w2.x; v.y += w2.y; v.z += w2.z; v.w += w2.w;
        }
    } else {
        if (c >= 128) return;
        v = *(const float4*)&Whh[(n - 128) * 128 + c];
    }
    ushort4 b;
    b.x = f2bf(v.x); b.y = f2bf(v.y); b.z = f2bf(v.z); b.w = f2bf(v.w);
    *(ushort4*)&wbuf[n * 384 + c] = b;
}

// ---------------- kernel 3: GRU via bf16 MFMA ----------------
// block = 256 threads (4 waves), 32 messages/block, K=384, N=512 outputs.
// wave w owns channels [32w, 32w+32) of each gate (8 N-tiles of 16), so
// r/z/i_n/h_n for a channel land at identical (lane,reg) slots -> register epilogue.
#define GMB 32
__global__ __launch_bounds__(256) void k_gru(
    const float* __restrict__ memp, const float* __restrict__ lup,
    const float* __restrict__ tp, const float* __restrict__ msgp,
    const int* __restrict__ srcp, const int* __restrict__ dstp,
    const float* __restrict__ twp, const float* __restrict__ tbp,
    const unsigned short* __restrict__ wbuf,
    const float* __restrict__ bih, const float* __restrict__ bhh,
    const int* __restrict__ last_pos,
    float* __restrict__ mem_new, float* __restrict__ lu_new, float* __restrict__ denom)
{
    __shared__ alignas(16) unsigned short Xs[32][392];   // 384 + 8 pad (2-way bank alias = free)
    __shared__ int sid[GMB], sother[GMB], se[GMB], slast[GMB];
    __shared__ float st[GMB], sdt[GMB];

    int tid = threadIdx.x;
    int i0 = blockIdx.x * GMB;
    if (tid < GMB) {
        int i = i0 + tid;
        int e = (i < NE) ? i : (i - NE);
        int id    = (i < NE) ? srcp[e] : dstp[e];
        int other = (i < NE) ? dstp[e] : srcp[e];
        sid[tid] = id; sother[tid] = other; se[tid] = e;
        float tt = tp[e];
        st[tid] = tt;
        sdt[tid] = tt - lup[id];
        slast[tid] = (last_pos[id] == i) ? 1 : 0;
    }
    __syncthreads();

    // stage X (bf16): 8 threads per row, 12 float4-groups each
    {
        int m = tid >> 3, li = tid & 7;
        int id = sid[m], oth = sother[m], e = se[m];
        float dt = sdt[m];
        #pragma unroll
        for (int j = 0; j < 12; ++j) {
            int c4 = li + 8 * j;               // 0..95
            float4 v;
            if (c4 < 32)      v = *(const float4*)&memp[id * D + c4 * 4];
            else if (c4 < 64) v = *(const float4*)&memp[oth * D + (c4 - 32) * 4];
            else if (c4 < 80) v = *(const float4*)&msgp[e * 64 + (c4 - 64) * 4];
            else {
                int c0 = (c4 - 80) * 4;
                v.x = cosf(dt * twp[c0 + 0] + tbp[c0 + 0]);
                v.y = cosf(dt * twp[c0 + 1] + tbp[c0 + 1]);
                v.z = cosf(dt * twp[c0 + 2] + tbp[c0 + 2]);
                v.w = cosf(dt * twp[c0 + 3] + tbp[c0 + 3]);
            }
            ushort4 b;
            b.x = f2bf(v.x); b.y = f2bf(v.y); b.z = f2bf(v.z); b.w = f2bf(v.w);
            *(ushort4*)&Xs[m][c4 * 4] = b;
        }
    }
    __syncthreads();

    int lane = tid & 63, w = tid >> 6;
    int q = lane >> 4, l15 = lane & 15;
    int q8 = q * 8, w32 = w * 32;

    f32x4 acc[2][4][2];
    #pragma unroll
    for (int mt = 0; mt < 2; ++mt)
        #pragma unroll
        for (int g = 0; g < 4; ++g)
            #pragma unroll
            for (int h = 0; h < 2; ++h)
                acc[mt][g][h] = (f32x4)(0.0f);

#define GRU_STEP(NG)                                                                      \
    {                                                                                     \
        const bf16x8 a0 = *(const bf16x8*)&Xs[l15][k0 + q8];                              \
        const bf16x8 a1 = *(const bf16x8*)&Xs[16 + l15][k0 + q8];                         \
        _Pragma("unroll")                                                                 \
        for (int g = 0; g < NG; ++g) {                                                    \
            _Pragma("unroll")                                                             \
            for (int h = 0; h < 2; ++h) {                                                 \
                const bf16x8 b = *(const bf16x8*)&wbuf[(g * 128 + w32 + h * 16 + l15) * 384 + k0 + q8]; \
                acc[0][g][h] = __builtin_amdgcn_mfma_f32_16x16x32_bf16(a0, b, acc[0][g][h], 0, 0, 0); \
                acc[1][g][h] = __builtin_amdgcn_mfma_f32_16x16x32_bf16(a1, b, acc[1][g][h], 0, 0, 0); \
            }                                                                             \
        }                                                                                 \
    }

    #pragma unroll 2
    for (int ks = 0; ks < 4; ++ks) { int k0 = ks * 32; GRU_STEP(4) }   // k<128: all 4 gates
    #pragma unroll 2
    for (int ks = 4; ks < 12; ++ks) { int k0 = ks * 32; GRU_STEP(3) }  // k>=128: h_n rows are zero
#undef GRU_STEP

    // epilogue: gates in registers; C/D layout col=lane&15, row=quad*4+reg
    #pragma unroll
    for (int h = 0; h < 2; ++h) {
        int c = w32 + h * 16 + l15;          // channel 0..127
        float br  = bih[c]       + bhh[c];
        float bz  = bih[128 + c] + bhh[128 + c];
        float bin = bih[256 + c];
        float bhn = bhh[256 + c];
        #pragma unroll
        for (int mt = 0; mt < 2; ++mt) {
            #pragma unroll
            for (int reg = 0; reg < 4; ++reg) {
                int m = mt * 16 + q * 4 + reg;
                if (slast[m]) {
                    float r  = sigmoidf_(acc[mt][0][h][reg] + br);
                    float zg = sigmoidf_(acc[mt][1][h][reg] + bz);
                    float n  = tanhf(acc[mt][2][h][reg] + bin + r * (acc[mt][3][h][reg] + bhn));
                    float hv = memp[sid[m] * D + c];               // fp32 h for the zg*h path
                    mem_new[sid[m] * D + c] = (1.f - zg) * n + zg * hv;
                }
            }
        }
    }
    if (tid < GMB && slast[tid]) {
        int id = sid[tid];
        lu_new[id] = fmaxf(lup[id], st[tid]);
        denom[id * 2] = 0.f; denom[id * 2 + 1] = 0.f;   // dst nodes are a subset of touched nodes
    }
}

// ---------------- kernel 4: skip connection z = Wskip@mem_new + bskip (touched rows) ----
#define SMB 16
__global__ __launch_bounds__(128) void k_skip(
    const int* __restrict__ srcp, const int* __restrict__ dstp,
    const int* __restrict__ last_pos, const float* __restrict__ mem_new,
    const float* __restrict__ Wskip, const float* __restrict__ bskip,
    float* __restrict__ zbuf)
{
    __shared__ float Xf[SMB][D];
    __shared__ int sid[SMB], slast[SMB];
    int tid = threadIdx.x;
    int i0 = blockIdx.x * SMB;
    if (tid < SMB) {
        int i = i0 + tid;
        int id = (i < NE) ? srcp[i] : dstp[i - NE];
        sid[tid] = id;
        slast[tid] = (last_pos[id] == i) ? 1 : 0;
    }
    __syncthreads();
    for (int m = 0; m < SMB; ++m)
        Xf[m][tid] = slast[m] ? mem_new[sid[m] * D + tid] : 0.f;
    __syncthreads();
    float acc[SMB];
    #pragma unroll
    for (int m = 0; m < SMB; ++m) acc[m] = 0.f;
    const float4* wr = (const float4*)(Wskip + tid * D);
    for (int k4 = 0; k4 < D / 4; ++k4) {
        float4 w = wr[k4];
        #pragma unroll
        for (int m = 0; m < SMB; ++m) {
            float4 x = ((const float4*)Xf[m])[k4];
            acc[m] += w.x * x.x + w.y * x.y + w.z * x.z + w.w * x.w;
        }
    }
    float b = bskip[tid];
    for (int m = 0; m < SMB; ++m)
        if (slast[m]) zbuf[sid[m] * D + tid] = acc[m] + b;
}

// ---------------- kernel 5: per-edge k,v,q + logits + exp + denom ----------------
#define AEB 8
__global__ __launch_bounds__(384) void k_attnA(
    const int* __restrict__ srcp, const int* __restrict__ dstp,
    const float* __restrict__ tp, const float* __restrict__ msgp,
    const float* __restrict__ twp, const float* __restrict__ tbp,
    const float* __restrict__ lu_new, const float* __restrict__ mem_new,
    const float* __restrict__ Wq, const float* __restrict__ bq,
    const float* __restrict__ Wk, const float* __restrict__ bk,
    const float* __restrict__ Wv, const float* __restrict__ bv,
    const float* __restrict__ We,
    float* __restrict__ vbuf, float* __restrict__ abuf, float* __restrict__ denom)
{
    __shared__ float Xf[AEB][GDIM];         // [mem_s(128) | mem_d(128) | te(64) | msg(64)]
    __shared__ float kL[AEB][D], qL[AEB][D];
    __shared__ int ssrc[AEB], sdst[AEB];
    __shared__ float srel[AEB];
    int tid = threadIdx.x;
    int e0 = blockIdx.x * AEB;
    if (tid < AEB) {
        int e = e0 + tid;
        int s = srcp[e], dd = dstp[e];
        ssrc[tid] = s; sdst[tid] = dd;
        srel[tid] = lu_new[s] - tp[e];      // rel_t (uses NEW last_update)
    }
    __syncthreads();
    {
        int c = tid;
        for (int m = 0; m < AEB; ++m) {
            float val;
            if (c < D)               val = mem_new[ssrc[m] * D + c];
            else if (c < 2 * D)      val = mem_new[sdst[m] * D + (c - D)];
            else if (c < 2 * D + 64) val = cosf(srel[m] * twp[c - 2 * D] + tbp[c - 2 * D]);
            else                     val = msgp[(e0 + m) * 64 + (c - (2 * D + 64))];
            Xf[m][c] = val;
        }
    }
    __syncthreads();
    int role = tid >> 7, j = tid & 127;
    float acc[AEB];
    if (role < 2) {
        const float* Wm = (role == 0) ? Wk : Wv;
        float b = ((role == 0) ? bk : bv)[j];
        #pragma unroll
        for (int m = 0; m < AEB; ++m) acc[m] = b;
        const float4* wm4 = (const float4*)(Wm + j * D);
        const float4* we4 = (const float4*)(We + j * D);
        for (int k4 = 0; k4 < D / 4; ++k4) {
            float4 wa = wm4[k4], wb = we4[k4];
            #pragma unroll
            for (int m = 0; m < AEB; ++m) {
                float4 xs = ((const float4*)Xf[m])[k4];       // mem_s
                float4 xe = ((const float4*)Xf[m])[64 + k4];  // edge attr [te|msg]
                acc[m] += wa.x * xs.x + wa.y * xs.y + wa.z * xs.z + wa.w * xs.w
                        + wb.x * xe.x + wb.y * xe.y + wb.z * xe.z + wb.w * xe.w;
            }
        }
    } else {
        float b = bq[j];
        #pragma unroll
        for (int m = 0; m < AEB; ++m) acc[m] = b;
        const float4* wq4 = (const float4*)(Wq + j * D);
        for (int k4 = 0; k4 < D / 4; ++k4) {
            float4 wa = wq4[k4];
            #pragma unroll
            for (int m = 0; m < AEB; ++m) {
                float4 xd = ((const float4*)Xf[m])[32 + k4];  // mem_d
                acc[m] += wa.x * xd.x + wa.y * xd.y + wa.z * xd.z + wa.w * xd.w;
            }
        }
    }
    #pragma unroll
    for (int m = 0; m < AEB; ++m) {
        if (role == 0)       kL[m][j] = acc[m];
        else if (role == 1)  vbuf[(e0 + m) * D + j] = acc[m];
        else                 qL[m][j] = acc[m];
    }
    __syncthreads();
    // logits; exp without max-subtract (|logit| small -> fp32 exp exact enough; same math)
    int w = tid >> 6, lane = tid & 63;
    for (int pr = w; pr < 2 * AEB; pr += 6) {
        int m = pr >> 1, h = pr & 1;
        float prod = qL[m][h * 64 + lane] * kL[m][h * 64 + lane];
        #pragma unroll
        for (int off = 32; off; off >>= 1) prod += __shfl_down(prod, off);
        if (lane == 0) {
            float a = expf(prod * 0.125f);                 // / sqrt(64)
            abuf[(e0 + m) * 2 + h] = a;
            atomicAdd(&denom[sdst[m] * 2 + h], a);
        }
    }
}

// ---------------- kernel 6: weighted scatter of v into z ----------------
__global__ void k_attnB(const int* __restrict__ dstp,
                        const float* __restrict__ abuf, const float* __restrict__ denom,
                        const float* __restrict__ vbuf, float* __restrict__ zbuf)
{
    int g = blockIdx.x * blockDim.x + threadIdx.x;    // exactly NE*128 threads
    int e = g >> 7, c = g & 127, h = c >> 6;
    int dd = dstp[e];
    float attn = abuf[e * 2 + h] / denom[dd * 2 + h];
    atomicAdd(&zbuf[dd * D + c], attn * vbuf[e * D + c]);
}

// ---------------- kernel 7: link predictor ----------------
#define LMB 8
__global__ __launch_bounds__(128) void k_link(
    const int* __restrict__ srcp, const int* __restrict__ dstp,
    const float* __restrict__ zbuf,
    const float* __restrict__ Wls, const float* __restrict__ bls,
    const float* __restrict__ Wld, const float* __restrict__ bld,
    const float* __restrict__ Wlf, const float* __restrict__ blf,
    float* __restrict__ outp)
{
    __shared__ float Xs_[LMB][D], Xd_[LMB][D];
    __shared__ int ss[LMB], sd[LMB];
    __shared__ float red[LMB][2];
    int tid = threadIdx.x;
    int e0 = blockIdx.x * LMB;
    if (tid < LMB) { ss[tid] = srcp[e0 + tid]; sd[tid] = dstp[e0 + tid]; }
    __syncthreads();
    for (int m = 0; m < LMB; ++m) {
        Xs_[m][tid] = zbuf[ss[m] * D + tid];
        Xd_[m][tid] = zbuf[sd[m] * D + tid];
    }
    __syncthreads();
    float acc[LMB];
    float binit = bls[tid] + bld[tid];
    #pragma unroll
    for (int m = 0; m < LMB; ++m) acc[m] = binit;
    const float4* ws4 = (const float4*)(Wls + tid * D);
    const float4* wd4 = (const float4*)(Wld + tid * D);
    for (int k4 = 0; k4 < D / 4; ++k4) {
        float4 wa = ws4[k4], wb = wd4[k4];
        #pragma unroll
        for (int m = 0; m < LMB; ++m) {
            float4 xs = ((const float4*)Xs_[m])[k4];
            float4 xd = ((const float4*)Xd_[m])[k4];
            acc[m] += wa.x * xs.x + wa.y * xs.y + wa.z * xs.z + wa.w * xs.w
                    + wb.x * xd.x + wb.y * xd.y + wb.z * xd.z + wb.w * xd.w;
        }
    }
    float wlf = Wlf[tid];
    int w = tid >> 6, lane = tid & 63;
    #pragma unroll
    for (int m = 0; m < LMB; ++m) {
        float part = fmaxf(acc[m], 0.f) * wlf;
        #pragma unroll
        for (int off = 32; off; off >>= 1) part += __shfl_down(part, off);
        if (lane == 0) red[m][w] = part;
    }
    __syncthreads();
    if (tid < LMB) outp[e0 + tid] = red[tid][0] + red[tid][1] + blf[0];
}

extern "C" void kernel_launch(void* const* d_in, const int* in_sizes, int n_in,
                              void* d_out, int out_size, void* d_ws, size_t ws_size,
                              hipStream_t stream)
{
    const float* memory      = (const float*)d_in[0];
    const float* last_update = (const float*)d_in[1];
    const float* t           = (const float*)d_in[2];
    const float* msg         = (const float*)d_in[3];
    const int*   src         = (const int*)d_in[4];
    const int*   dst         = (const int*)d_in[5];
    const float* time_w      = (const float*)d_in[6];
    const float* time_b      = (const float*)d_in[7];
    const float* gru_Wih     = (const float*)d_in[8];
    const float* gru_bih     = (const float*)d_in[9];
    const float* gru_Whh     = (const float*)d_in[10];
    const float* gru_bhh     = (const float*)d_in[11];
    const float* Wq          = (const float*)d_in[12];
    const float* bq          = (const float*)d_in[13];
    const float* Wk          = (const float*)d_in[14];
    const float* bk          = (const float*)d_in[15];
    const float* Wv          = (const float*)d_in[16];
    const float* bv          = (const float*)d_in[17];
    const float* We          = (const float*)d_in[18];
    const float* Wskip       = (const float*)d_in[19];
    const float* bskip       = (const float*)d_in[20];
    const float* Wls         = (const float*)d_in[21];
    const float* bls         = (const float*)d_in[22];
    const float* Wld         = (const float*)d_in[23];
    const float* bld         = (const float*)d_in[24];
    const float* Wlf         = (const float*)d_in[25];
    const float* blf         = (const float*)d_in[26];
    float* outp = (float*)d_out;

    // workspace layout (bytes), total 234,000,000
    char* ws = (char*)d_ws;
    int*   last_pos = (int*)  (ws + 0);            // N int
    float* lu_new   = (float*)(ws + 800000);       // N
    float* denom    = (float*)(ws + 1600000);      // 2N
    float* abuf     = (float*)(ws + 3200000);      // 2E
    float* vbuf     = (float*)(ws + 3600000);      // E*128 (written in k_attnA)
    unsigned short* wbuf = (unsigned short*)(ws + 3600000); // 512*384 bf16, overlaps vbuf:
                                                   // wbuf live only during k_prepw..k_gru,
                                                   // vbuf written later in k_attnA. Safe.
    float* mem_new  = (float*)(ws + 29200000);     // N*128 (touched rows only valid)
    float* zbuf     = (float*)(ws + 131600000);    // N*128 (touched rows only valid)

    k_init   <<<(NN + 255) / 256, 256, 0, stream>>>(last_pos);
    k_lastpos<<<(2 * NE + 255) / 256, 256, 0, stream>>>(src, dst, last_pos);
    k_prepw  <<<(512 * 96 + 255) / 256, 256, 0, stream>>>(gru_Wih, gru_Whh, wbuf);
    k_gru    <<<2 * NE / GMB, 256, 0, stream>>>(memory, last_update, t, msg, src, dst,
                 time_w, time_b, wbuf, gru_bih, gru_bhh, last_pos,
                 mem_new, lu_new, denom);
    k_skip   <<<2 * NE / SMB, 128, 0, stream>>>(src, dst, last_pos, mem_new, Wskip, bskip, zbuf);
    k_attnA  <<<NE / AEB, 384, 0, stream>>>(src, dst, t, msg, time_w, time_b, lu_new, mem_new,
                 Wq, bq, Wk, bk, Wv, bv, We, vbuf, abuf, denom);
    k_attnB  <<<NE * D / 256, 256, 0, stream>>>(dst, abuf, denom, vbuf, zbuf);
    k_link   <<<NE / LMB, 128, 0, stream>>>(src, dst, zbuf, Wls, bls, Wld, bld, Wlf, blf, outp);
}

// Round 3
// 613.830 us; speedup vs baseline: 3.7363x; 1.6257x over previous
//
#include <hip/hip_runtime.h>
#include <math.h>

#define NN 200000
#define NE 50000
#define D 128
#define GDIM 384   // 3*MEM

__device__ __forceinline__ float sigmoidf_(float x) { return 1.0f / (1.0f + expf(-x)); }

// round-to-nearest-even fp32 -> bf16 bits
__device__ __forceinline__ unsigned short f2bf(float f) {
    unsigned int u = __float_as_uint(f);
    u = (u + 0x7fffu + ((u >> 16) & 1u)) >> 16;
    return (unsigned short)u;
}
__device__ __forceinline__ float bf2f(unsigned short b) {
    return __uint_as_float(((unsigned int)b) << 16);
}

typedef short bf16x8 __attribute__((ext_vector_type(8)));
typedef float f32x4  __attribute__((ext_vector_type(4)));

// ---------------- kernel 1: init last_pos ----------------
__global__ void k_init(int* __restrict__ last_pos) {
    int i = blockIdx.x * blockDim.x + threadIdx.x;
    if (i < NN) last_pos[i] = -1;
}

// ---------------- kernel 2: scatter max position ----------------
__global__ void k_lastpos(const int* __restrict__ src, const int* __restrict__ dst,
                          int* __restrict__ last_pos) {
    int i = blockIdx.x * blockDim.x + threadIdx.x;
    if (i < 2 * NE) {
        int id = (i < NE) ? src[i] : dst[i - NE];
        atomicMax(&last_pos[id], i);
    }
}

// ---------------- kernel 2b: build all fused bf16 weights ----------------
// wgru[512][384]: rows 0..255 (r,z fused) = Wih + [Whh|0]; 256..383 = Wih_n;
//                 384..511 = Whh_n in cols 0..127 (cols>=128 never read)
// wattn[384][384]: rows 0..127 (k) = [Wk | We | -]; 128..255 (v) = [Wv | We | -];
//                  256..383 (q) = [- | - | Wq]   ('-' regions never read)
// wskip[128][128] = Wskip
__global__ void k_prepw(const float* __restrict__ Wih, const float* __restrict__ Whh,
                        const float* __restrict__ Wk, const float* __restrict__ Wv,
                        const float* __restrict__ Wq, const float* __restrict__ We,
                        const float* __restrict__ Wskip,
                        unsigned short* __restrict__ wgru,
                        unsigned short* __restrict__ wattn,
                        unsigned short* __restrict__ wskp) {
    int idx = blockIdx.x * 256 + threadIdx.x;     // 49152 + 36864 + 4096 groups
    float4 v;
    unsigned short* dst;
    if (idx < 49152) {                            // gru
        int n = idx / 96;
        int c = (idx - n * 96) * 4;
        if (n < 384) {
            v = *(const float4*)&Wih[n * 384 + c];
            if (n < 256 && c < 128) {
                const float4 w2 = *(const float4*)&Whh[n * 128 + c];
                v.x += w2.x; v.y += w2.y; v.z += w2.z; v.w += w2.w;
            }
        } else {
            if (c >= 128) return;
            v = *(const float4*)&Whh[(n - 128) * 128 + c];
        }
        dst = &wgru[n * 384 + c];
    } else if (idx < 49152 + 36864) {             // attn
        int i2 = idx - 49152;
        int n = i2 / 96;
        int c = (i2 - n * 96) * 4;
        if (n < 256) {
            const float* Wm = (n < 128) ? Wk : Wv;
            int nn = n & 127;
            if (c < 128)       v = *(const float4*)&Wm[nn * 128 + c];
            else if (c < 256)  v = *(const float4*)&We[nn * 128 + (c - 128)];
            else return;
        } else {
            if (c < 256) return;
            v = *(const float4*)&Wq[(n - 256) * 128 + (c - 256)];
        }
        dst = &wattn[n * 384 + c];
    } else {                                      // skip
        int i3 = idx - 49152 - 36864;
        int n = i3 / 32;
        int c = (i3 - n * 32) * 4;
        v = *(const float4*)&Wskip[n * 128 + c];
        dst = &wskp[n * 128 + c];
    }
    ushort4 b;
    b.x = f2bf(v.x); b.y = f2bf(v.y); b.z = f2bf(v.z); b.w = f2bf(v.w);
    *(ushort4*)dst = b;
}

// ---------------- kernel 3: GRU via bf16 MFMA + fused skip GEMM ----------------
#define GMB 32
__global__ __launch_bounds__(256) void k_gru(
    const float* __restrict__ memp, const float* __restrict__ lup,
    const float* __restrict__ tp, const float* __restrict__ msgp,
    const int* __restrict__ srcp, const int* __restrict__ dstp,
    const float* __restrict__ twp, const float* __restrict__ tbp,
    const unsigned short* __restrict__ wgru,
    const float* __restrict__ bih, const float* __restrict__ bhh,
    const unsigned short* __restrict__ wskp, const float* __restrict__ bskip,
    const int* __restrict__ last_pos,
    float* __restrict__ mem_new, float* __restrict__ lu_new, float* __restrict__ denom,
    float* __restrict__ zbuf)
{
    __shared__ alignas(16) unsigned short Xs[32][392];   // 384 + 8 pad
    __shared__ int sid[GMB], sother[GMB], se[GMB], slast[GMB];
    __shared__ float st[GMB], sdt[GMB];

    int tid = threadIdx.x;
    int i0 = blockIdx.x * GMB;
    if (tid < GMB) {
        int i = i0 + tid;
        int e = (i < NE) ? i : (i - NE);
        int id    = (i < NE) ? srcp[e] : dstp[e];
        int other = (i < NE) ? dstp[e] : srcp[e];
        sid[tid] = id; sother[tid] = other; se[tid] = e;
        float tt = tp[e];
        st[tid] = tt;
        sdt[tid] = tt - lup[id];
        slast[tid] = (last_pos[id] == i) ? 1 : 0;
    }
    __syncthreads();

    // stage X (bf16): 8 threads per row, 12 float4-groups each
    {
        int m = tid >> 3, li = tid & 7;
        int id = sid[m], oth = sother[m], e = se[m];
        float dt = sdt[m];
        #pragma unroll
        for (int j = 0; j < 12; ++j) {
            int c4 = li + 8 * j;               // 0..95
            float4 v;
            if (c4 < 32)      v = *(const float4*)&memp[id * D + c4 * 4];
            else if (c4 < 64) v = *(const float4*)&memp[oth * D + (c4 - 32) * 4];
            else if (c4 < 80) v = *(const float4*)&msgp[e * 64 + (c4 - 64) * 4];
            else {
                int c0 = (c4 - 80) * 4;
                v.x = cosf(dt * twp[c0 + 0] + tbp[c0 + 0]);
                v.y = cosf(dt * twp[c0 + 1] + tbp[c0 + 1]);
                v.z = cosf(dt * twp[c0 + 2] + tbp[c0 + 2]);
                v.w = cosf(dt * twp[c0 + 3] + tbp[c0 + 3]);
            }
            ushort4 b;
            b.x = f2bf(v.x); b.y = f2bf(v.y); b.z = f2bf(v.z); b.w = f2bf(v.w);
            *(ushort4*)&Xs[m][c4 * 4] = b;
        }
    }
    __syncthreads();

    int lane = tid & 63, w = tid >> 6;
    int q = lane >> 4, l15 = lane & 15;
    int q8 = q * 8, w32 = w * 32;

    f32x4 acc[2][4][2];
    #pragma unroll
    for (int mt = 0; mt < 2; ++mt)
        #pragma unroll
        for (int g = 0; g < 4; ++g)
            #pragma unroll
            for (int h = 0; h < 2; ++h)
                acc[mt][g][h] = (f32x4)(0.0f);

#define GRU_STEP(NG)                                                                      \
    {                                                                                     \
        const bf16x8 a0 = *(const bf16x8*)&Xs[l15][k0 + q8];                              \
        const bf16x8 a1 = *(const bf16x8*)&Xs[16 + l15][k0 + q8];                         \
        _Pragma("unroll")                                                                 \
        for (int g = 0; g < NG; ++g) {                                                    \
            _Pragma("unroll")                                                             \
            for (int h = 0; h < 2; ++h) {                                                 \
                const bf16x8 b = *(const bf16x8*)&wgru[(g * 128 + w32 + h * 16 + l15) * 384 + k0 + q8]; \
                acc[0][g][h] = __builtin_amdgcn_mfma_f32_16x16x32_bf16(a0, b, acc[0][g][h], 0, 0, 0); \
                acc[1][g][h] = __builtin_amdgcn_mfma_f32_16x16x32_bf16(a1, b, acc[1][g][h], 0, 0, 0); \
            }                                                                             \
        }                                                                                 \
    }

    #pragma unroll 2
    for (int ks = 0; ks < 4; ++ks) { int k0 = ks * 32; GRU_STEP(4) }   // k<128: all 4 gates
    #pragma unroll 2
    for (int ks = 4; ks < 12; ++ks) { int k0 = ks * 32; GRU_STEP(3) }  // k>=128: h_n rows zero
#undef GRU_STEP

    // epilogue: gates in registers; C/D layout col=lane&15, row=quad*4+reg
    float nval[2][2][4];
    #pragma unroll
    for (int h = 0; h < 2; ++h) {
        int c = w32 + h * 16 + l15;          // channel 0..127
        float br  = bih[c]       + bhh[c];
        float bz  = bih[128 + c] + bhh[128 + c];
        float bin = bih[256 + c];
        float bhn = bhh[256 + c];
        #pragma unroll
        for (int mt = 0; mt < 2; ++mt) {
            #pragma unroll
            for (int reg = 0; reg < 4; ++reg) {
                int m = mt * 16 + q * 4 + reg;
                float val = 0.f;
                if (slast[m]) {
                    float r  = sigmoidf_(acc[mt][0][h][reg] + br);
                    float zg = sigmoidf_(acc[mt][1][h][reg] + bz);
                    float n  = tanhf(acc[mt][2][h][reg] + bin + r * (acc[mt][3][h][reg] + bhn));
                    float hv = memp[sid[m] * D + c];               // fp32 h for the zg*h path
                    val = (1.f - zg) * n + zg * hv;
                    mem_new[sid[m] * D + c] = val;
                }
                nval[h][mt][reg] = val;
            }
        }
    }
    if (tid < GMB && slast[tid]) {
        int id = sid[tid];
        lu_new[id] = fmaxf(lup[id], st[tid]);
        denom[id * 2] = 0.f; denom[id * 2 + 1] = 0.f;   // dst nodes subset of touched nodes
    }

    // ---- fused skip GEMM: z = Wskip @ mem_new + bskip (is_last rows) ----
    __syncthreads();                                   // all MFMA reads of Xs done
    #pragma unroll
    for (int h = 0; h < 2; ++h) {
        int c = w32 + h * 16 + l15;
        #pragma unroll
        for (int mt = 0; mt < 2; ++mt)
            #pragma unroll
            for (int reg = 0; reg < 4; ++reg)
                Xs[mt * 16 + q * 4 + reg][c] = f2bf(nval[h][mt][reg]);
    }
    __syncthreads();

    f32x4 acc2[2][2];
    #pragma unroll
    for (int mt = 0; mt < 2; ++mt)
        #pragma unroll
        for (int jj = 0; jj < 2; ++jj) acc2[mt][jj] = (f32x4)(0.0f);
    #pragma unroll
    for (int ks = 0; ks < 4; ++ks) {
        int k0 = ks * 32;
        const bf16x8 a0 = *(const bf16x8*)&Xs[l15][k0 + q8];
        const bf16x8 a1 = *(const bf16x8*)&Xs[16 + l15][k0 + q8];
        #pragma unroll
        for (int jj = 0; jj < 2; ++jj) {
            int nt = w + 4 * jj;
            const bf16x8 b = *(const bf16x8*)&wskp[(nt * 16 + l15) * 128 + k0 + q8];
            acc2[0][jj] = __builtin_amdgcn_mfma_f32_16x16x32_bf16(a0, b, acc2[0][jj], 0, 0, 0);
            acc2[1][jj] = __builtin_amdgcn_mfma_f32_16x16x32_bf16(a1, b, acc2[1][jj], 0, 0, 0);
        }
    }
    #pragma unroll
    for (int jj = 0; jj < 2; ++jj) {
        int ch = (w + 4 * jj) * 16 + l15;
        float b = bskip[ch];
        #pragma unroll
        for (int mt = 0; mt < 2; ++mt)
            #pragma unroll
            for (int reg = 0; reg < 4; ++reg) {
                int m = mt * 16 + q * 4 + reg;
                if (slast[m]) zbuf[sid[m] * D + ch] = acc2[mt][jj][reg] + b;
            }
    }
}

// ---------------- kernel 5: attn k,v,q via bf16 MFMA + logits + denom ----------------
// 32 edges/block, 256 threads. X = [mem_s(128) | te(64) msg(64) | mem_d(128)].
// N-tiles 0..23 (k:0..7, v:8..15, q:16..23); wave w owns nt = w+4j, j=0..5.
// k/v use K in [0,256); q uses K in [256,384).
#define AMB 32
__global__ __launch_bounds__(256) void k_attnA(
    const int* __restrict__ srcp, const int* __restrict__ dstp,
    const float* __restrict__ tp, const float* __restrict__ msgp,
    const float* __restrict__ twp, const float* __restrict__ tbp,
    const float* __restrict__ lu_new, const float* __restrict__ mem_new,
    const unsigned short* __restrict__ wattn,
    const float* __restrict__ bq, const float* __restrict__ bk, const float* __restrict__ bv,
    unsigned short* __restrict__ vbuf, float* __restrict__ abuf, float* __restrict__ denom)
{
    __shared__ alignas(16) unsigned short Xs[32][392];
    __shared__ float kL[32][D], qL[32][D];
    __shared__ int ssrc[AMB], sdst[AMB];
    __shared__ float srel[AMB];
    int tid = threadIdx.x;
    int e0 = blockIdx.x * AMB;
    if (tid < AMB) {
        int e = e0 + tid; if (e >= NE) e = NE - 1;     // tail clamp
        int s = srcp[e], dd = dstp[e];
        ssrc[tid] = s; sdst[tid] = dd;
        srel[tid] = lu_new[s] - tp[e];                 // rel_t (NEW last_update)
    }
    __syncthreads();
    {   // stage X bf16: 8 threads/edge, 12 float4-groups
        int m = tid >> 3, li = tid & 7;
        int e = e0 + m; if (e >= NE) e = NE - 1;
        int s = ssrc[m], dd = sdst[m];
        float rel = srel[m];
        #pragma unroll
        for (int j = 0; j < 12; ++j) {
            int c4 = li + 8 * j;
            float4 v;
            if (c4 < 32)      v = *(const float4*)&mem_new[s * D + c4 * 4];
            else if (c4 < 48) {
                int c0 = (c4 - 32) * 4;
                v.x = cosf(rel * twp[c0 + 0] + tbp[c0 + 0]);
                v.y = cosf(rel * twp[c0 + 1] + tbp[c0 + 1]);
                v.z = cosf(rel * twp[c0 + 2] + tbp[c0 + 2]);
                v.w = cosf(rel * twp[c0 + 3] + tbp[c0 + 3]);
            }
            else if (c4 < 64) v = *(const float4*)&msgp[e * 64 + (c4 - 48) * 4];
            else              v = *(const float4*)&mem_new[dd * D + (c4 - 64) * 4];
            ushort4 b;
            b.x = f2bf(v.x); b.y = f2bf(v.y); b.z = f2bf(v.z); b.w = f2bf(v.w);
            *(ushort4*)&Xs[m][c4 * 4] = b;
        }
    }
    __syncthreads();

    int lane = tid & 63, w = tid >> 6;
    int q = lane >> 4, l15 = lane & 15;
    int q8 = q * 8;

    f32x4 acc[2][6];
    #pragma unroll
    for (int mt = 0; mt < 2; ++mt)
        #pragma unroll
        for (int jj = 0; jj < 6; ++jj) acc[mt][jj] = (f32x4)(0.0f);

    #pragma unroll 2
    for (int ks = 0; ks < 8; ++ks) {                   // K tiles for k,v gates
        int k0 = ks * 32;
        const bf16x8 a0 = *(const bf16x8*)&Xs[l15][k0 + q8];
        const bf16x8 a1 = *(const bf16x8*)&Xs[16 + l15][k0 + q8];
        #pragma unroll
        for (int jj = 0; jj < 4; ++jj) {               // nt = w+4jj in 0..15
            int nt = w + 4 * jj;
            const bf16x8 b = *(const bf16x8*)&wattn[(nt * 16 + l15) * 384 + k0 + q8];
            acc[0][jj] = __builtin_amdgcn_mfma_f32_16x16x32_bf16(a0, b, acc[0][jj], 0, 0, 0);
            acc[1][jj] = __builtin_amdgcn_mfma_f32_16x16x32_bf16(a1, b, acc[1][jj], 0, 0, 0);
        }
    }
    #pragma unroll 2
    for (int ks = 8; ks < 12; ++ks) {                  // K tiles for q gate
        int k0 = ks * 32;
        const bf16x8 a0 = *(const bf16x8*)&Xs[l15][k0 + q8];
        const bf16x8 a1 = *(const bf16x8*)&Xs[16 + l15][k0 + q8];
        #pragma unroll
        for (int jj = 4; jj < 6; ++jj) {               // nt in 16..23
            int nt = w + 4 * jj;
            const bf16x8 b = *(const bf16x8*)&wattn[(nt * 16 + l15) * 384 + k0 + q8];
            acc[0][jj] = __builtin_amdgcn_mfma_f32_16x16x32_bf16(a0, b, acc[0][jj], 0, 0, 0);
            acc[1][jj] = __builtin_amdgcn_mfma_f32_16x16x32_bf16(a1, b, acc[1][jj], 0, 0, 0);
        }
    }

    // epilogue: k,q -> LDS fp32; v -> bf16 vbuf
    #pragma unroll
    for (int jj = 0; jj < 6; ++jj) {
        int nt = w + 4 * jj;
        int gate = nt >> 3;
        int ch = (nt & 7) * 16 + l15;
        float bias = (gate == 0) ? bk[ch] : (gate == 1) ? bv[ch] : bq[ch];
        #pragma unroll
        for (int mt = 0; mt < 2; ++mt)
            #pragma unroll
            for (int reg = 0; reg < 4; ++reg) {
                int m = mt * 16 + q * 4 + reg;
                float val = acc[mt][jj][reg] + bias;
                if (gate == 0)      kL[m][ch] = val;
                else if (gate == 2) qL[m][ch] = val;
                else if (e0 + m < NE) vbuf[(e0 + m) * D + ch] = f2bf(val);
            }
    }
    __syncthreads();
    // logits; exp without max-subtract (|logit| small -> same math in fp32)
    for (int pr = w; pr < 2 * AMB; pr += 4) {
        int m = pr >> 1, h = pr & 1;
        if (e0 + m >= NE) continue;
        float prod = qL[m][h * 64 + lane] * kL[m][h * 64 + lane];
        #pragma unroll
        for (int off = 32; off; off >>= 1) prod += __shfl_down(prod, off);
        if (lane == 0) {
            float a = expf(prod * 0.125f);             // / sqrt(64)
            abuf[(e0 + m) * 2 + h] = a;
            atomicAdd(&denom[sdst[m] * 2 + h], a);
        }
    }
}

// ---------------- kernel 6: weighted scatter of v into z ----------------
__global__ void k_attnB(const int* __restrict__ dstp,
                        const float* __restrict__ abuf, const float* __restrict__ denom,
                        const unsigned short* __restrict__ vbuf, float* __restrict__ zbuf)
{
    int g = blockIdx.x * blockDim.x + threadIdx.x;    // exactly NE*128 threads
    int e = g >> 7, c = g & 127, h = c >> 6;
    int dd = dstp[e];
    float attn = abuf[e * 2 + h] / denom[dd * 2 + h];
    atomicAdd(&zbuf[dd * D + c], attn * bf2f(vbuf[e * D + c]));
}

// ---------------- kernel 7: link predictor ----------------
#define LMB 8
__global__ __launch_bounds__(128) void k_link(
    const int* __restrict__ srcp, const int* __restrict__ dstp,
    const float* __restrict__ zbuf,
    const float* __restrict__ Wls, const float* __restrict__ bls,
    const float* __restrict__ Wld, const float* __restrict__ bld,
    const float* __restrict__ Wlf, const float* __restrict__ blf,
    float* __restrict__ outp)
{
    __shared__ float Xs_[LMB][D], Xd_[LMB][D];
    __shared__ int ss[LMB], sd[LMB];
    __shared__ float red[LMB][2];
    int tid = threadIdx.x;
    int e0 = blockIdx.x * LMB;
    if (tid < LMB) { ss[tid] = srcp[e0 + tid]; sd[tid] = dstp[e0 + tid]; }
    __syncthreads();
    for (int m = 0; m < LMB; ++m) {
        Xs_[m][tid] = zbuf[ss[m] * D + tid];
        Xd_[m][tid] = zbuf[sd[m] * D + tid];
    }
    __syncthreads();
    float acc[LMB];
    float binit = bls[tid] + bld[tid];
    #pragma unroll
    for (int m = 0; m < LMB; ++m) acc[m] = binit;
    const float4* ws4 = (const float4*)(Wls + tid * D);
    const float4* wd4 = (const float4*)(Wld + tid * D);
    for (int k4 = 0; k4 < D / 4; ++k4) {
        float4 wa = ws4[k4], wb = wd4[k4];
        #pragma unroll
        for (int m = 0; m < LMB; ++m) {
            float4 xs = ((const float4*)Xs_[m])[k4];
            float4 xd = ((const float4*)Xd_[m])[k4];
            acc[m] += wa.x * xs.x + wa.y * xs.y + wa.z * xs.z + wa.w * xs.w
                    + wb.x * xd.x + wb.y * xd.y + wb.z * xd.z + wb.w * xd.w;
        }
    }
    float wlf = Wlf[tid];
    int w = tid >> 6, lane = tid & 63;
    #pragma unroll
    for (int m = 0; m < LMB; ++m) {
        float part = fmaxf(acc[m], 0.f) * wlf;
        #pragma unroll
        for (int off = 32; off; off >>= 1) part += __shfl_down(part, off);
        if (lane == 0) red[m][w] = part;
    }
    __syncthreads();
    if (tid < LMB) outp[e0 + tid] = red[tid][0] + red[tid][1] + blf[0];
}

extern "C" void kernel_launch(void* const* d_in, const int* in_sizes, int n_in,
                              void* d_out, int out_size, void* d_ws, size_t ws_size,
                              hipStream_t stream)
{
    const float* memory      = (const float*)d_in[0];
    const float* last_update = (const float*)d_in[1];
    const float* t           = (const float*)d_in[2];
    const float* msg         = (const float*)d_in[3];
    const int*   src         = (const int*)d_in[4];
    const int*   dst         = (const int*)d_in[5];
    const float* time_w      = (const float*)d_in[6];
    const float* time_b      = (const float*)d_in[7];
    const float* gru_Wih     = (const float*)d_in[8];
    const float* gru_bih     = (const float*)d_in[9];
    const float* gru_Whh     = (const float*)d_in[10];
    const float* gru_bhh     = (const float*)d_in[11];
    const float* Wq          = (const float*)d_in[12];
    const float* bq          = (const float*)d_in[13];
    const float* Wk          = (const float*)d_in[14];
    const float* bk          = (const float*)d_in[15];
    const float* Wv          = (const float*)d_in[16];
    const float* bv          = (const float*)d_in[17];
    const float* We          = (const float*)d_in[18];
    const float* Wskip       = (const float*)d_in[19];
    const float* bskip       = (const float*)d_in[20];
    const float* Wls         = (const float*)d_in[21];
    const float* bls         = (const float*)d_in[22];
    const float* Wld         = (const float*)d_in[23];
    const float* bld         = (const float*)d_in[24];
    const float* Wlf         = (const float*)d_in[25];
    const float* blf         = (const float*)d_in[26];
    float* outp = (float*)d_out;

    // workspace layout (bytes)
    char* ws = (char*)d_ws;
    int*   last_pos = (int*)  (ws + 0);              // N int
    float* lu_new   = (float*)(ws + 800000);         // N
    float* denom    = (float*)(ws + 1600000);        // 2N
    float* abuf     = (float*)(ws + 3200000);        // 2E
    unsigned short* vbuf  = (unsigned short*)(ws + 3600000);   // E*128 bf16 (12.8 MB)
    unsigned short* wgru  = (unsigned short*)(ws + 16400000);  // 512*384 bf16
    unsigned short* wattn = (unsigned short*)(ws + 16800000);  // 384*384 bf16
    unsigned short* wskp  = (unsigned short*)(ws + 17100000);  // 128*128 bf16
    float* mem_new  = (float*)(ws + 29200000);       // N*128 (touched rows only valid)
    float* zbuf     = (float*)(ws + 131600000);      // N*128 (touched rows only valid)

    k_init   <<<(NN + 255) / 256, 256, 0, stream>>>(last_pos);
    k_lastpos<<<(2 * NE + 255) / 256, 256, 0, stream>>>(src, dst, last_pos);
    k_prepw  <<<(49152 + 36864 + 4096) / 256, 256, 0, stream>>>(
                 gru_Wih, gru_Whh, Wk, Wv, Wq, We, Wskip, wgru, wattn, wskp);
    k_gru    <<<2 * NE / GMB, 256, 0, stream>>>(memory, last_update, t, msg, src, dst,
                 time_w, time_b, wgru, gru_bih, gru_bhh, wskp, bskip, last_pos,
                 mem_new, lu_new, denom, zbuf);
    k_attnA  <<<(NE + AMB - 1) / AMB, 256, 0, stream>>>(src, dst, t, msg, time_w, time_b,
                 lu_new, mem_new, wattn, bq, bk, bv, vbuf, abuf, denom);
    k_attnB  <<<NE * D / 256, 256, 0, stream>>>(dst, abuf, denom, vbuf, zbuf);
    k_link   <<<NE / LMB, 128, 0, stream>>>(src, dst, zbuf, Wls, bls, Wld, bld, Wlf, blf, outp);
}

// Round 4
// 609.180 us; speedup vs baseline: 3.7648x; 1.0076x over previous
//
#include <hip/hip_runtime.h>
#include <math.h>

#define NN 200000
#define NE 50000
#define D 128
#define GDIM 384   // 3*MEM

__device__ __forceinline__ float sigmoidf_(float x) { return 1.0f / (1.0f + expf(-x)); }

// round-to-nearest-even fp32 -> bf16 bits
__device__ __forceinline__ unsigned short f2bf(float f) {
    unsigned int u = __float_as_uint(f);
    u = (u + 0x7fffu + ((u >> 16) & 1u)) >> 16;
    return (unsigned short)u;
}
__device__ __forceinline__ float bf2f(unsigned short b) {
    return __uint_as_float(((unsigned int)b) << 16);
}

typedef short bf16x8 __attribute__((ext_vector_type(8)));
typedef float f32x4  __attribute__((ext_vector_type(4)));

// ---------------- kernel 1: init last_pos + count + prep bf16 weights ----------------
// wgru[512][384]: rows 0..255 (r,z fused) = Wih + [Whh|0]; 256..383 = Wih_n;
//                 384..511 = Whh_n in cols 0..127 (cols>=128 never read)
// wattn[384][384]: rows 0..127 (k) = [Wk | We | -]; 128..255 (v) = [Wv | We | -];
//                  256..383 (q) = [- | - | Wq]
// wskip[128][128] = Wskip
__global__ void k_initprep(const float* __restrict__ Wih, const float* __restrict__ Whh,
                           const float* __restrict__ Wk, const float* __restrict__ Wv,
                           const float* __restrict__ Wq, const float* __restrict__ We,
                           const float* __restrict__ Wskip,
                           unsigned short* __restrict__ wgru,
                           unsigned short* __restrict__ wattn,
                           unsigned short* __restrict__ wskp,
                           int* __restrict__ last_pos, int* __restrict__ count) {
    int idx = blockIdx.x * 256 + threadIdx.x;
    if (idx == 0) *count = 0;
    if (idx < NN) last_pos[idx] = -1;
    if (idx >= 49152 + 36864 + 4096) return;
    float4 v;
    unsigned short* dstp;
    if (idx < 49152) {                            // gru
        int n = idx / 96;
        int c = (idx - n * 96) * 4;
        if (n < 384) {
            v = *(const float4*)&Wih[n * 384 + c];
            if (n < 256 && c < 128) {
                const float4 w2 = *(const float4*)&Whh[n * 128 + c];
                v.x += w2.x; v.y += w2.y; v.z += w2.z; v.w += w2.w;
            }
        } else {
            if (c >= 128) return;
            v = *(const float4*)&Whh[(n - 128) * 128 + c];
        }
        dstp = &wgru[n * 384 + c];
    } else if (idx < 49152 + 36864) {             // attn
        int i2 = idx - 49152;
        int n = i2 / 96;
        int c = (i2 - n * 96) * 4;
        if (n < 256) {
            const float* Wm = (n < 128) ? Wk : Wv;
            int nn = n & 127;
            if (c < 128)       v = *(const float4*)&Wm[nn * 128 + c];
            else if (c < 256)  v = *(const float4*)&We[nn * 128 + (c - 128)];
            else return;
        } else {
            if (c < 256) return;
            v = *(const float4*)&Wq[(n - 256) * 128 + (c - 256)];
        }
        dstp = &wattn[n * 384 + c];
    } else {                                      // skip
        int i3 = idx - 49152 - 36864;
        int n = i3 / 32;
        int c = (i3 - n * 32) * 4;
        v = *(const float4*)&Wskip[n * 128 + c];
        dstp = &wskp[n * 128 + c];
    }
    ushort4 b;
    b.x = f2bf(v.x); b.y = f2bf(v.y); b.z = f2bf(v.z); b.w = f2bf(v.w);
    *(ushort4*)dstp = b;
}

// ---------------- kernel 2: scatter max position ----------------
__global__ void k_lastpos(const int* __restrict__ src, const int* __restrict__ dst,
                          int* __restrict__ last_pos) {
    int i = blockIdx.x * blockDim.x + threadIdx.x;
    if (i < 2 * NE) {
        int id = (i < NE) ? src[i] : dst[i - NE];
        atomicMax(&last_pos[id], i);
    }
}

// ---------------- kernel 2c: compact is_last message indices ----------------
__global__ void k_compact(const int* __restrict__ src, const int* __restrict__ dst,
                          const int* __restrict__ last_pos,
                          int* __restrict__ count, int* __restrict__ clist) {
    int i = blockIdx.x * blockDim.x + threadIdx.x;
    if (i < 2 * NE) {
        int id = (i < NE) ? src[i] : dst[i - NE];
        if (last_pos[id] == i) clist[atomicAdd(count, 1)] = i;
    }
}

// ---------------- kernel 3: GRU via bf16 MFMA + fused skip GEMM (compacted) ----------
#define GMB 32
__global__ __launch_bounds__(256) void k_gru(
    const float* __restrict__ memp, const float* __restrict__ lup,
    const float* __restrict__ tp, const float* __restrict__ msgp,
    const int* __restrict__ srcp, const int* __restrict__ dstp,
    const float* __restrict__ twp, const float* __restrict__ tbp,
    const unsigned short* __restrict__ wgru,
    const float* __restrict__ bih, const float* __restrict__ bhh,
    const unsigned short* __restrict__ wskp, const float* __restrict__ bskip,
    const int* __restrict__ countp, const int* __restrict__ clist,
    unsigned short* __restrict__ mem_new, float* __restrict__ lu_new,
    float* __restrict__ denom, float* __restrict__ zbuf)
{
    __shared__ alignas(16) unsigned short Xs[32][392];   // 384 + 8 pad
    __shared__ int sid[GMB], sother[GMB], se[GMB];
    __shared__ float st[GMB], sdt[GMB];

    int cnt = *countp;
    int base = blockIdx.x * GMB;
    if (base >= cnt) return;
    int tid = threadIdx.x;
    if (tid < GMB) {
        int ii = base + tid; if (ii >= cnt) ii = cnt - 1;   // tail dup (idempotent)
        int i = clist[ii];
        int e = (i < NE) ? i : (i - NE);
        int id    = (i < NE) ? srcp[e] : dstp[e];
        int other = (i < NE) ? dstp[e] : srcp[e];
        sid[tid] = id; sother[tid] = other; se[tid] = e;
        float tt = tp[e];
        st[tid] = tt;
        sdt[tid] = tt - lup[id];
    }
    __syncthreads();

    // stage X (bf16): 8 threads per row, 12 float4-groups each
    {
        int m = tid >> 3, li = tid & 7;
        int id = sid[m], oth = sother[m], e = se[m];
        float dt = sdt[m];
        #pragma unroll
        for (int j = 0; j < 12; ++j) {
            int c4 = li + 8 * j;               // 0..95
            float4 v;
            if (c4 < 32)      v = *(const float4*)&memp[id * D + c4 * 4];
            else if (c4 < 64) v = *(const float4*)&memp[oth * D + (c4 - 32) * 4];
            else if (c4 < 80) v = *(const float4*)&msgp[e * 64 + (c4 - 64) * 4];
            else {
                int c0 = (c4 - 80) * 4;
                v.x = cosf(dt * twp[c0 + 0] + tbp[c0 + 0]);
                v.y = cosf(dt * twp[c0 + 1] + tbp[c0 + 1]);
                v.z = cosf(dt * twp[c0 + 2] + tbp[c0 + 2]);
                v.w = cosf(dt * twp[c0 + 3] + tbp[c0 + 3]);
            }
            ushort4 b;
            b.x = f2bf(v.x); b.y = f2bf(v.y); b.z = f2bf(v.z); b.w = f2bf(v.w);
            *(ushort4*)&Xs[m][c4 * 4] = b;
        }
    }
    __syncthreads();

    int lane = tid & 63, w = tid >> 6;
    int q = lane >> 4, l15 = lane & 15;
    int q8 = q * 8, w32 = w * 32;

    f32x4 acc[2][4][2];
    #pragma unroll
    for (int mt = 0; mt < 2; ++mt)
        #pragma unroll
        for (int g = 0; g < 4; ++g)
            #pragma unroll
            for (int h = 0; h < 2; ++h)
                acc[mt][g][h] = (f32x4)(0.0f);

#define GRU_STEP(NG)                                                                      \
    {                                                                                     \
        const bf16x8 a0 = *(const bf16x8*)&Xs[l15][k0 + q8];                              \
        const bf16x8 a1 = *(const bf16x8*)&Xs[16 + l15][k0 + q8];                         \
        _Pragma("unroll")                                                                 \
        for (int g = 0; g < NG; ++g) {                                                    \
            _Pragma("unroll")                                                             \
            for (int h = 0; h < 2; ++h) {                                                 \
                const bf16x8 b = *(const bf16x8*)&wgru[(g * 128 + w32 + h * 16 + l15) * 384 + k0 + q8]; \
                acc[0][g][h] = __builtin_amdgcn_mfma_f32_16x16x32_bf16(a0, b, acc[0][g][h], 0, 0, 0); \
                acc[1][g][h] = __builtin_amdgcn_mfma_f32_16x16x32_bf16(a1, b, acc[1][g][h], 0, 0, 0); \
            }                                                                             \
        }                                                                                 \
    }

    #pragma unroll 2
    for (int ks = 0; ks < 4; ++ks) { int k0 = ks * 32; GRU_STEP(4) }   // k<128: all 4 gates
    #pragma unroll 2
    for (int ks = 4; ks < 12; ++ks) { int k0 = ks * 32; GRU_STEP(3) }  // k>=128: h_n rows zero
#undef GRU_STEP

    // epilogue: gates in registers; C/D layout col=lane&15, row=quad*4+reg
    float nval[2][2][4];
    #pragma unroll
    for (int h = 0; h < 2; ++h) {
        int c = w32 + h * 16 + l15;          // channel 0..127
        float br  = bih[c]       + bhh[c];
        float bz  = bih[128 + c] + bhh[128 + c];
        float bin = bih[256 + c];
        float bhn = bhh[256 + c];
        #pragma unroll
        for (int mt = 0; mt < 2; ++mt) {
            #pragma unroll
            for (int reg = 0; reg < 4; ++reg) {
                int m = mt * 16 + q * 4 + reg;
                float r  = sigmoidf_(acc[mt][0][h][reg] + br);
                float zg = sigmoidf_(acc[mt][1][h][reg] + bz);
                float n  = tanhf(acc[mt][2][h][reg] + bin + r * (acc[mt][3][h][reg] + bhn));
                float hv = memp[sid[m] * D + c];               // fp32 h, L1-hot from staging
                nval[h][mt][reg] = (1.f - zg) * n + zg * hv;
            }
        }
    }
    if (tid < GMB && base + tid < cnt) {
        int id = sid[tid];
        lu_new[id] = fmaxf(lup[id], st[tid]);
        denom[id * 2] = 0.f; denom[id * 2 + 1] = 0.f;   // dst nodes subset of touched nodes
    }

    // ---- mem_new (bf16) via LDS + fused skip GEMM ----
    __syncthreads();                                   // all MFMA reads of Xs done
    #pragma unroll
    for (int h = 0; h < 2; ++h) {
        int c = w32 + h * 16 + l15;
        #pragma unroll
        for (int mt = 0; mt < 2; ++mt)
            #pragma unroll
            for (int reg = 0; reg < 4; ++reg)
                Xs[mt * 16 + q * 4 + reg][c] = f2bf(nval[h][mt][reg]);
    }
    __syncthreads();

    {   // vectorized bf16 mem_new store: 16B per store, 2 per thread
        int m = tid >> 3, li = tid & 7;
        uint4* drow = (uint4*)&mem_new[sid[m] * D];
        const uint4* srow = (const uint4*)&Xs[m][0];
        drow[li]     = srow[li];
        drow[li + 8] = srow[li + 8];
    }

    f32x4 acc2[2][2];
    #pragma unroll
    for (int mt = 0; mt < 2; ++mt)
        #pragma unroll
        for (int jj = 0; jj < 2; ++jj) acc2[mt][jj] = (f32x4)(0.0f);
    #pragma unroll
    for (int ks = 0; ks < 4; ++ks) {
        int k0 = ks * 32;
        const bf16x8 a0 = *(const bf16x8*)&Xs[l15][k0 + q8];
        const bf16x8 a1 = *(const bf16x8*)&Xs[16 + l15][k0 + q8];
        #pragma unroll
        for (int jj = 0; jj < 2; ++jj) {
            int nt = w + 4 * jj;
            const bf16x8 b = *(const bf16x8*)&wskp[(nt * 16 + l15) * 128 + k0 + q8];
            acc2[0][jj] = __builtin_amdgcn_mfma_f32_16x16x32_bf16(a0, b, acc2[0][jj], 0, 0, 0);
            acc2[1][jj] = __builtin_amdgcn_mfma_f32_16x16x32_bf16(a1, b, acc2[1][jj], 0, 0, 0);
        }
    }
    #pragma unroll
    for (int jj = 0; jj < 2; ++jj) {
        int ch = (w + 4 * jj) * 16 + l15;
        float b = bskip[ch];
        #pragma unroll
        for (int mt = 0; mt < 2; ++mt)
            #pragma unroll
            for (int reg = 0; reg < 4; ++reg) {
                int m = mt * 16 + q * 4 + reg;
                zbuf[sid[m] * D + ch] = acc2[mt][jj][reg] + b;
            }
    }
}

// ---------------- kernel 5: attn k,v,q via bf16 MFMA + logits + denom ----------------
// 32 edges/block, 256 threads. X = [mem_s(128) | te(64) msg(64) | mem_d(128)] bf16.
#define AMB 32
__global__ __launch_bounds__(256) void k_attnA(
    const int* __restrict__ srcp, const int* __restrict__ dstp,
    const float* __restrict__ tp, const float* __restrict__ msgp,
    const float* __restrict__ twp, const float* __restrict__ tbp,
    const float* __restrict__ lu_new, const unsigned short* __restrict__ mem_new,
    const unsigned short* __restrict__ wattn,
    const float* __restrict__ bq, const float* __restrict__ bk, const float* __restrict__ bv,
    unsigned short* __restrict__ vbuf, float* __restrict__ abuf, float* __restrict__ denom)
{
    __shared__ alignas(16) unsigned short Xs[32][392];
    __shared__ float kL[32][D], qL[32][D];
    __shared__ int ssrc[AMB], sdst[AMB];
    __shared__ float srel[AMB];
    int tid = threadIdx.x;
    int e0 = blockIdx.x * AMB;
    if (tid < AMB) {
        int e = e0 + tid; if (e >= NE) e = NE - 1;     // tail clamp
        int s = srcp[e], dd = dstp[e];
        ssrc[tid] = s; sdst[tid] = dd;
        srel[tid] = lu_new[s] - tp[e];                 // rel_t (NEW last_update)
    }
    __syncthreads();
    {   // stage X bf16: 8 threads/edge; mem rows copied as 16B chunks (already bf16)
        int m = tid >> 3, li = tid & 7;
        int e = e0 + m; if (e >= NE) e = NE - 1;
        int s = ssrc[m], dd = sdst[m];
        float rel = srel[m];
        uint4* xrow = (uint4*)&Xs[m][0];
        const uint4* srow = (const uint4*)&mem_new[s * D];
        const uint4* drow = (const uint4*)&mem_new[dd * D];
        #pragma unroll
        for (int j = 0; j < 2; ++j) {
            xrow[li + 8 * j]      = srow[li + 8 * j];      // mem_s -> shorts [0,128)
            xrow[32 + li + 8 * j] = drow[li + 8 * j];      // mem_d -> shorts [256,384)
        }
        {   // te -> shorts [128,192): 8 cos per thread
            int c0 = li * 8;
            ushort4 lo, hi;
            lo.x = f2bf(cosf(rel * twp[c0 + 0] + tbp[c0 + 0]));
            lo.y = f2bf(cosf(rel * twp[c0 + 1] + tbp[c0 + 1]));
            lo.z = f2bf(cosf(rel * twp[c0 + 2] + tbp[c0 + 2]));
            lo.w = f2bf(cosf(rel * twp[c0 + 3] + tbp[c0 + 3]));
            hi.x = f2bf(cosf(rel * twp[c0 + 4] + tbp[c0 + 4]));
            hi.y = f2bf(cosf(rel * twp[c0 + 5] + tbp[c0 + 5]));
            hi.z = f2bf(cosf(rel * twp[c0 + 6] + tbp[c0 + 6]));
            hi.w = f2bf(cosf(rel * twp[c0 + 7] + tbp[c0 + 7]));
            *(ushort4*)&Xs[m][128 + c0]     = lo;
            *(ushort4*)&Xs[m][128 + c0 + 4] = hi;
        }
        {   // msg -> shorts [192,256)
            float4 a = *(const float4*)&msgp[e * 64 + li * 8];
            float4 b = *(const float4*)&msgp[e * 64 + li * 8 + 4];
            ushort4 lo, hi;
            lo.x = f2bf(a.x); lo.y = f2bf(a.y); lo.z = f2bf(a.z); lo.w = f2bf(a.w);
            hi.x = f2bf(b.x); hi.y = f2bf(b.y); hi.z = f2bf(b.z); hi.w = f2bf(b.w);
            *(ushort4*)&Xs[m][192 + li * 8]     = lo;
            *(ushort4*)&Xs[m][192 + li * 8 + 4] = hi;
        }
    }
    __syncthreads();

    int lane = tid & 63, w = tid >> 6;
    int q = lane >> 4, l15 = lane & 15;
    int q8 = q * 8;

    f32x4 acc[2][6];
    #pragma unroll
    for (int mt = 0; mt < 2; ++mt)
        #pragma unroll
        for (int jj = 0; jj < 6; ++jj) acc[mt][jj] = (f32x4)(0.0f);

    #pragma unroll 2
    for (int ks = 0; ks < 8; ++ks) {                   // K tiles for k,v gates
        int k0 = ks * 32;
        const bf16x8 a0 = *(const bf16x8*)&Xs[l15][k0 + q8];
        const bf16x8 a1 = *(const bf16x8*)&Xs[16 + l15][k0 + q8];
        #pragma unroll
        for (int jj = 0; jj < 4; ++jj) {               // nt = w+4jj in 0..15
            int nt = w + 4 * jj;
            const bf16x8 b = *(const bf16x8*)&wattn[(nt * 16 + l15) * 384 + k0 + q8];
            acc[0][jj] = __builtin_amdgcn_mfma_f32_16x16x32_bf16(a0, b, acc[0][jj], 0, 0, 0);
            acc[1][jj] = __builtin_amdgcn_mfma_f32_16x16x32_bf16(a1, b, acc[1][jj], 0, 0, 0);
        }
    }
    #pragma unroll 2
    for (int ks = 8; ks < 12; ++ks) {                  // K tiles for q gate
        int k0 = ks * 32;
        const bf16x8 a0 = *(const bf16x8*)&Xs[l15][k0 + q8];
        const bf16x8 a1 = *(const bf16x8*)&Xs[16 + l15][k0 + q8];
        #pragma unroll
        for (int jj = 4; jj < 6; ++jj) {               // nt in 16..23
            int nt = w + 4 * jj;
            const bf16x8 b = *(const bf16x8*)&wattn[(nt * 16 + l15) * 384 + k0 + q8];
            acc[0][jj] = __builtin_amdgcn_mfma_f32_16x16x32_bf16(a0, b, acc[0][jj], 0, 0, 0);
            acc[1][jj] = __builtin_amdgcn_mfma_f32_16x16x32_bf16(a1, b, acc[1][jj], 0, 0, 0);
        }
    }

    // epilogue: k,q -> LDS fp32; v -> bf16 vbuf
    #pragma unroll
    for (int jj = 0; jj < 6; ++jj) {
        int nt = w + 4 * jj;
        int gate = nt >> 3;
        int ch = (nt & 7) * 16 + l15;
        float bias = (gate == 0) ? bk[ch] : (gate == 1) ? bv[ch] : bq[ch];
        #pragma unroll
        for (int mt = 0; mt < 2; ++mt)
            #pragma unroll
            for (int reg = 0; reg < 4; ++reg) {
                int m = mt * 16 + q * 4 + reg;
                float val = acc[mt][jj][reg] + bias;
                if (gate == 0)      kL[m][ch] = val;
                else if (gate == 2) qL[m][ch] = val;
                else if (e0 + m < NE) vbuf[(e0 + m) * D + ch] = f2bf(val);
            }
    }
    __syncthreads();
    // logits; exp without max-subtract (|logit| small -> same math in fp32)
    for (int pr = w; pr < 2 * AMB; pr += 4) {
        int m = pr >> 1, h = pr & 1;
        if (e0 + m >= NE) continue;
        float prod = qL[m][h * 64 + lane] * kL[m][h * 64 + lane];
        #pragma unroll
        for (int off = 32; off; off >>= 1) prod += __shfl_down(prod, off);
        if (lane == 0) {
            float a = expf(prod * 0.125f);             // / sqrt(64)
            abuf[(e0 + m) * 2 + h] = a;
            atomicAdd(&denom[sdst[m] * 2 + h], a);
        }
    }
}

// ---------------- kernel 6: weighted scatter of v into z ----------------
__global__ void k_attnB(const int* __restrict__ dstp,
                        const float* __restrict__ abuf, const float* __restrict__ denom,
                        const unsigned short* __restrict__ vbuf, float* __restrict__ zbuf)
{
    int g = blockIdx.x * blockDim.x + threadIdx.x;    // exactly NE*128 threads
    int e = g >> 7, c = g & 127, h = c >> 6;
    int dd = dstp[e];
    float attn = abuf[e * 2 + h] / denom[dd * 2 + h];
    atomicAdd(&zbuf[dd * D + c], attn * bf2f(vbuf[e * D + c]));
}

// ---------------- kernel 7: link predictor ----------------
#define LMB 8
__global__ __launch_bounds__(128) void k_link(
    const int* __restrict__ srcp, const int* __restrict__ dstp,
    const float* __restrict__ zbuf,
    const float* __restrict__ Wls, const float* __restrict__ bls,
    const float* __restrict__ Wld, const float* __restrict__ bld,
    const float* __restrict__ Wlf, const float* __restrict__ blf,
    float* __restrict__ outp)
{
    __shared__ float Xs_[LMB][D], Xd_[LMB][D];
    __shared__ int ss[LMB], sd[LMB];
    __shared__ float red[LMB][2];
    int tid = threadIdx.x;
    int e0 = blockIdx.x * LMB;
    if (tid < LMB) { ss[tid] = srcp[e0 + tid]; sd[tid] = dstp[e0 + tid]; }
    __syncthreads();
    for (int m = 0; m < LMB; ++m) {
        Xs_[m][tid] = zbuf[ss[m] * D + tid];
        Xd_[m][tid] = zbuf[sd[m] * D + tid];
    }
    __syncthreads();
    float acc[LMB];
    float binit = bls[tid] + bld[tid];
    #pragma unroll
    for (int m = 0; m < LMB; ++m) acc[m] = binit;
    const float4* ws4 = (const float4*)(Wls + tid * D);
    const float4* wd4 = (const float4*)(Wld + tid * D);
    for (int k4 = 0; k4 < D / 4; ++k4) {
        float4 wa = ws4[k4], wb = wd4[k4];
        #pragma unroll
        for (int m = 0; m < LMB; ++m) {
            float4 xs = ((const float4*)Xs_[m])[k4];
            float4 xd = ((const float4*)Xd_[m])[k4];
            acc[m] += wa.x * xs.x + wa.y * xs.y + wa.z * xs.z + wa.w * xs.w
                    + wb.x * xd.x + wb.y * xd.y + wb.z * xd.z + wb.w * xd.w;
        }
    }
    float wlf = Wlf[tid];
    int w = tid >> 6, lane = tid & 63;
    #pragma unroll
    for (int m = 0; m < LMB; ++m) {
        float part = fmaxf(acc[m], 0.f) * wlf;
        #pragma unroll
        for (int off = 32; off; off >>= 1) part += __shfl_down(part, off);
        if (lane == 0) red[m][w] = part;
    }
    __syncthreads();
    if (tid < LMB) outp[e0 + tid] = red[tid][0] + red[tid][1] + blf[0];
}

extern "C" void kernel_launch(void* const* d_in, const int* in_sizes, int n_in,
                              void* d_out, int out_size, void* d_ws, size_t ws_size,
                              hipStream_t stream)
{
    const float* memory      = (const float*)d_in[0];
    const float* last_update = (const float*)d_in[1];
    const float* t           = (const float*)d_in[2];
    const float* msg         = (const float*)d_in[3];
    const int*   src         = (const int*)d_in[4];
    const int*   dst         = (const int*)d_in[5];
    const float* time_w      = (const float*)d_in[6];
    const float* time_b      = (const float*)d_in[7];
    const float* gru_Wih     = (const float*)d_in[8];
    const float* gru_bih     = (const float*)d_in[9];
    const float* gru_Whh     = (const float*)d_in[10];
    const float* gru_bhh     = (const float*)d_in[11];
    const float* Wq          = (const float*)d_in[12];
    const float* bq          = (const float*)d_in[13];
    const float* Wk          = (const float*)d_in[14];
    const float* bk          = (const float*)d_in[15];
    const float* Wv          = (const float*)d_in[16];
    const float* bv          = (const float*)d_in[17];
    const float* We          = (const float*)d_in[18];
    const float* Wskip       = (const float*)d_in[19];
    const float* bskip       = (const float*)d_in[20];
    const float* Wls         = (const float*)d_in[21];
    const float* bls         = (const float*)d_in[22];
    const float* Wld         = (const float*)d_in[23];
    const float* bld         = (const float*)d_in[24];
    const float* Wlf         = (const float*)d_in[25];
    const float* blf         = (const float*)d_in[26];
    float* outp = (float*)d_out;

    // workspace layout (bytes), all offsets 16B-aligned
    char* ws = (char*)d_ws;
    int*   last_pos = (int*)  (ws + 0);               // N int (800,000)
    float* lu_new   = (float*)(ws + 800000);          // N
    float* denom    = (float*)(ws + 1600000);         // 2N
    float* abuf     = (float*)(ws + 3200000);         // 2E
    int*   count    = (int*)  (ws + 3600000);         // 1 (+pad)
    int*   clist    = (int*)  (ws + 3600016);         // 2E int
    unsigned short* vbuf    = (unsigned short*)(ws + 4000016);   // E*128 bf16
    unsigned short* wgru    = (unsigned short*)(ws + 16800016);  // 512*384 bf16
    unsigned short* wattn   = (unsigned short*)(ws + 17193232);  // 384*384 bf16
    unsigned short* wskp    = (unsigned short*)(ws + 17488144);  // 128*128 bf16
    unsigned short* mem_new = (unsigned short*)(ws + 17520912);  // N*128 bf16 (touched rows)
    float* zbuf     = (float*)(ws + 68720912);        // N*128 fp32 (touched rows)

    k_initprep<<<(NN + 255) / 256, 256, 0, stream>>>(
                 gru_Wih, gru_Whh, Wk, Wv, Wq, We, Wskip, wgru, wattn, wskp,
                 last_pos, count);
    k_lastpos <<<(2 * NE + 255) / 256, 256, 0, stream>>>(src, dst, last_pos);
    k_compact <<<(2 * NE + 255) / 256, 256, 0, stream>>>(src, dst, last_pos, count, clist);
    k_gru     <<<2 * NE / GMB, 256, 0, stream>>>(memory, last_update, t, msg, src, dst,
                 time_w, time_b, wgru, gru_bih, gru_bhh, wskp, bskip, count, clist,
                 mem_new, lu_new, denom, zbuf);
    k_attnA   <<<(NE + AMB - 1) / AMB, 256, 0, stream>>>(src, dst, t, msg, time_w, time_b,
                 lu_new, mem_new, wattn, bq, bk, bv, vbuf, abuf, denom);
    k_attnB   <<<NE * D / 256, 256, 0, stream>>>(dst, abuf, denom, vbuf, zbuf);
    k_link    <<<NE / LMB, 128, 0, stream>>>(src, dst, zbuf, Wls, bls, Wld, bld, Wlf, blf, outp);
}